// Round 1
// baseline (150.455 us; speedup 1.0000x reference)
//
#include <hip/hip_runtime.h>

typedef _Float16 f16x2 __attribute__((ext_vector_type(2)));
typedef __fp16  fp16x2 __attribute__((ext_vector_type(2)));

// Problem constants
constexpr int NKW  = 25, NK = 625;
constexpr int WPADR = 132;                  // reference padded width
constexpr int RST   = 35;                   // LDS row stride in uint2 (+1 anti-conflict)
constexpr int IMG   = 8;                    // images per block (weight reuse factor)
constexpr int NSLAB = 6;                    // ki slabs: NKI = {5,4,4,4,4,4}
constexpr int MAXR  = 30;                   // max staged rows (slab 0)

union U2H { unsigned int u; f16x2 h; fp16x2 p; };

__device__ __forceinline__ float dot2acc(unsigned int a, unsigned int b, float c) {
    U2H ua, ub; ua.u = a; ub.u = b;
#if __has_builtin(__builtin_amdgcn_fdot2)
    return __builtin_amdgcn_fdot2(ua.h, ub.h, c, false);
#else
    return c + (float)ua.h.x * (float)ub.h.x + (float)ua.h.y * (float)ub.h.y;
#endif
}

// R14: NO-WORKSPACE experiment. The rocprof top-5 is 100% 256-MiB
// fillBufferAligned dispatches (41 us each) == d_ws poison fills; neither of
// our kernels exceeds 41 us, yet dur_us=121 -> the timed region must contain
// the ws poison. Theory: consuming d_ws is what puts those fills in the timed
// stream. So: gather weights IN-BLOCK from dense W (mathematically identical
// to gather_wp output, verified slot-for-slot), never touch d_ws, drop the
// gather_wp launch. In-kernel gather = ~50 scattered L2-resident loads/thread,
// once per block, reused across IMG=8 images.
//
// Retained from earlier rounds: XCD-pinning swizzle (all 6 ki-slabs of an
// image group share (flat % 8) -> same XCD -> halo/band re-reads of x hit
// that XCD's L2), double-buffered LDS pipeline, f16 fdot2 compute.
__global__ __launch_bounds__(256, 4)
void lc2d_pipe(const float* __restrict__ x, const float* __restrict__ Wfull,
               const float* __restrict__ bias, float* __restrict__ out) {
    __shared__ uint2 xs[2][MAXR * RST];     // 16800 B

    // swizzle: flat -> (grp, slab) with grp % 8 == flat % 8 (XCD-pinned)
    const int flat = blockIdx.x;            // 0..767
    const int xcd  = flat & 7;
    const int j_   = flat >> 3;             // 0..95
    const int grp  = xcd + 8 * (j_ & 15);   // 0..127
    const int slab = j_ >> 4;               // 0..5
    const int K0   = slab ? (4 * slab + 1) : 0;   // 0,5,9,13,17,21
    const int NKI  = slab ? 4 : 5;
    const int R    = 5 * NKI + 5;           // staged rows: 30 / 25
    const int NOUT = NKI * NKW;             // 125 / 100
    const int row0 = 5 * K0 - 2;            // unpadded row of staged idx 0
    const int tid  = threadIdx.x;
    const int b0   = grp * IMG;

    // pair mapping: wave w, lane l -> pair = w*32 + (l&31), half = (l>>5)&1
    const int lane = tid & 63;
    const int pairidx = (tid >> 6) * 32 + (lane & 31);
    const int half = (lane >> 5) & 1;
    const bool active = pairidx < NOUT;
    const int ki_l = pairidx / 25;
    const int kj   = pairidx - ki_l * 25;
    const int k    = (K0 + ki_l) * NKW + kj;
    const int di0  = half * 5;              // this thread's 5 di rows

    // ---- weights: in-block gather from dense W, ONCE per block ----
    // Identical values to the old gather_wp workspace path: slot s of row
    // (di, j-half pb) holds W[row, kj*5 + (s-o)] for 0 <= s-o < 10, else 0,
    // with o = (5*kj+2)&3 matching the aligned LDS window.
    uint4 wq[10];
    float bval = 0.f;
    if (active) {
        const int o = (5 * kj + 2) & 3;
#pragma unroll
        for (int j = 0; j < 10; ++j) {
            const int di = di0 + (j >> 1), pb = (j & 1) * 8;
            unsigned int uu[4];
#pragma unroll
            for (int m = 0; m < 4; ++m) {
                float f0 = 0.f, f1 = 0.f;
                const int j0 = pb + 2 * m - o, j1 = pb + 2 * m + 1 - o;
                const size_t rowb = (size_t)(((K0 + ki_l) * 5 + di) * WPADR + kj * 5);
                if (j0 >= 0 && j0 < 10) f0 = Wfull[(rowb + j0) * NK + k];
                if (j1 >= 0 && j1 < 10) f1 = Wfull[(rowb + j1) * NK + k];
                U2H u; u.p = __builtin_amdgcn_cvt_pkrtz(f0, f1);
                uu[m] = u.u;
            }
            wq[j] = make_uint4(uu[0], uu[1], uu[2], uu[3]);
        }
        if (half == 0) bval = bias[k];
    }

    // ---- boundary zeros, once, both buffers (q=0 left pad, q=33 right pad) ----
    for (int i = tid; i < 4 * R; i += 256)
        xs[i & 1][(i >> 2) * RST + ((i >> 1) & 1) * 33] = make_uint2(0u, 0u);

    // ---- pipeline phases ----
    auto stage_load = [&](int img, float4* tmp) {
        const float* xb = x + ((size_t)(b0 + img) << 14);
#pragma unroll
        for (int t = 0; t < 4; ++t) {
            const int i = tid + t * 256;
            tmp[t] = make_float4(0.f, 0.f, 0.f, 0.f);
            if (i < R * 32) {
                const int idx = i >> 5, q = i & 31;
                const int r = row0 + idx;
                if (r >= 0 && r < 128)
                    tmp[t] = *reinterpret_cast<const float4*>(xb + (r << 7) + (q << 2));
            }
        }
    };
    auto stage_write = [&](int buf, const float4* tmp) {
#pragma unroll
        for (int t = 0; t < 4; ++t) {
            const int i = tid + t * 256;
            if (i < R * 32) {
                const int idx = i >> 5, q = (i & 31) + 1;
                U2H u0, u1;
                u0.p = __builtin_amdgcn_cvt_pkrtz(tmp[t].x, tmp[t].y);
                u1.p = __builtin_amdgcn_cvt_pkrtz(tmp[t].z, tmp[t].w);
                xs[buf][idx * RST + q] = make_uint2(u0.u, u1.u);
            }
        }
    };

    // tmp[j&1] holds image j's loads. Prologue: img0 staged, img1 in flight.
    float4 tmpA[4], tmpB[4];
    stage_load(0, tmpA);
    stage_write(0, tmpA);
    stage_load(1, tmpB);
    __syncthreads();

    for (int i = 0; i < IMG; ++i) {
        // issue image i+2's loads into the tmp slot just freed (image i's)
        if (i + 2 < IMG) stage_load(i + 2, (i & 1) ? tmpB : tmpA);

        float acc0 = 0.f, acc1 = 0.f;
        if (active) {
            const uint2* base = xs[i & 1] + (5 * ki_l + di0) * RST + ((5 * kj + 2) >> 2);
#pragma unroll
            for (int d = 0; d < 5; ++d) {
                const uint2* rowp = base + d * RST;
                const uint2 a0 = rowp[0], a1 = rowp[1], a2 = rowp[2], a3 = rowp[3];
                const uint4 wA = wq[2 * d], wB = wq[2 * d + 1];
                acc0 = dot2acc(a0.x, wA.x, acc0);
                acc1 = dot2acc(a0.y, wA.y, acc1);
                acc0 = dot2acc(a1.x, wA.z, acc0);
                acc1 = dot2acc(a1.y, wA.w, acc1);
                acc0 = dot2acc(a2.x, wB.x, acc0);
                acc1 = dot2acc(a2.y, wB.y, acc1);
                acc0 = dot2acc(a3.x, wB.z, acc0);
                acc1 = dot2acc(a3.y, wB.w, acc1);
            }
        }
        // combine lane pair (l, l^32) within the wave; half 0 stores
        float acc = acc0 + acc1;
        float other = __shfl_xor(acc, 32, 64);
        if (active && half == 0)
            out[(size_t)(b0 + i) * NK + k] = acc + other + bval;

        // write image i+1 into the other LDS buffer; waits only its own loads
        if (i + 1 < IMG) stage_write((i + 1) & 1, (i & 1) ? tmpA : tmpB);
        __syncthreads();
    }
}

extern "C" void kernel_launch(void* const* d_in, const int* in_sizes, int n_in,
                              void* d_out, int out_size, void* d_ws, size_t ws_size,
                              hipStream_t stream) {
    const float* x    = (const float*)d_in[0];
    const float* W    = (const float*)d_in[1];
    const float* bias = (const float*)d_in[2];
    float* out = (float*)d_out;

    (void)d_ws; (void)ws_size;              // deliberately unused: avoid ws poison fills
    const dim3 grid(128 * NSLAB);           // 768 blocks, XCD-swizzled in-kernel
    lc2d_pipe<<<grid, 256, 0, stream>>>(x, W, bias, out);
}

// Round 2
// 126.693 us; speedup vs baseline: 1.1876x; 1.1876x over previous
//
#include <hip/hip_runtime.h>

typedef _Float16 f16x2 __attribute__((ext_vector_type(2)));
typedef __fp16  fp16x2 __attribute__((ext_vector_type(2)));

// Problem constants
constexpr int NKW  = 25, NK = 625;
constexpr int WPADR = 132;                  // reference padded width
constexpr int WPT   = 160;                  // padded halves per (ki,kj) weight row
constexpr int RST   = 35;                   // LDS row stride in uint2 (+1 anti-conflict)
constexpr int RTOT  = 132;                  // staged rows: 2 pad + 128 + 2 pad
constexpr int NCHUNK = 5;                   // 5 * 128 pairs = 640 >= 625

union U2H { unsigned int u; f16x2 h; fp16x2 p; };

// ---- gather: dense W -> f16 weights, zero-padded 16-slot rows, TRANSPOSED ----
// wgpT as uint4[20][625]; slot j of output k holds padded halves 8j..8j+7.
// Real data at in-row slot o..o+9, o = (5*kj+2) & 3, matching aligned LDS
// window h0 = (5*kj+2) & ~3.  (unchanged, verified in earlier rounds)
__global__ void gather_wp(const float* __restrict__ W, _Float16* __restrict__ wgpT) {
    int t = blockIdx.x * 256 + threadIdx.x;
    if (t >= NK * WPT) return;
    int k = t / WPT, p = t % WPT;
    int di = p >> 4, s = p & 15;
    int ki = k / NKW, kj = k % NKW;
    int o = (5 * kj + 2) & 3;
    int j = s - o;
    float val = 0.f;
    if (j >= 0 && j < 10)
        val = W[(size_t)((ki * 5 + di) * WPADR + kj * 5 + j) * NK + k];
    wgpT[((size_t)(p >> 3) * NK + k) * 8 + (p & 7)] = (_Float16)val;
}

__device__ __forceinline__ float dot2acc(unsigned int a, unsigned int b, float c) {
    U2H ua, ub; ua.u = a; ub.u = b;
#if __has_builtin(__builtin_amdgcn_fdot2)
    return __builtin_amdgcn_fdot2(ua.h, ub.h, c, false);
#else
    return c + (float)ua.h.x * (float)ub.h.x + (float)ua.h.y * (float)ub.h.y;
#endif
}

// R15: ONE IMAGE PER BLOCK. R14 post-mortem: ws poison fills (~2x41us) are
// unconditional -> sunk cost; revert to ws/gather path. pipe<true> itself
// (~35us) is latency/delivery-bound (VALUBusy 9%, hbm 12%): the 6-slab
// structure stages 1.21x halo rows, runs 8 serial image phases x 2 barriers,
// and thrashes L2 (8MB/XCD working set vs 4MB). New structure: 1024 blocks,
// each stages its FULL padded image once (36.9KB LDS, 4 blocks/CU = whole
// grid resident in one shot), ONE barrier, then 5 register-chunks compute all
// 625 outputs with double-buffered coalesced weight loads from the 200KB
// L2-resident wgpT. x is read exactly once, perfectly coalesced: 64MB total.
template <bool USE_WG>
__global__ __launch_bounds__(256, 4)
void lc2d_img(const float* __restrict__ x, const _Float16* __restrict__ wgpT,
              const float* __restrict__ Wfull,
              const float* __restrict__ bias, float* __restrict__ out) {
    __shared__ uint2 xs[RTOT * RST];        // 36960 B -> 4 blocks/CU

    const int b    = blockIdx.x;            // one image per block
    const int tid  = threadIdx.x;
    const int lane = tid & 63;
    const int pairbase = (tid >> 6) * 32 + (lane & 31);  // 0..127
    const int half = lane >> 5;             // lane pair (l, l^32) shares pairbase
    const int di0  = half * 5;              // this thread's 5 di rows

    // ---- stage the full padded image as f16 into LDS (rows -2..129) ----
    // 132 rows x 32 float4 slots = 4224 items; 3 batches of 6/thread keeps
    // VGPR pressure low while all waves keep >=6 loads in flight.
    const float* xb = x + ((size_t)b << 14);
#pragma unroll 1
    for (int bt = 0; bt < 3; ++bt) {
        float4 tmp[6];
#pragma unroll
        for (int u = 0; u < 6; ++u) {
            const int i = tid + (bt * 6 + u) * 256;
            tmp[u] = make_float4(0.f, 0.f, 0.f, 0.f);
            if (i < RTOT * 32) {
                const int idx = i >> 5, q = i & 31, r = idx - 2;
                if (r >= 0 && r < 128)
                    tmp[u] = *reinterpret_cast<const float4*>(xb + (r << 7) + (q << 2));
            }
        }
#pragma unroll
        for (int u = 0; u < 6; ++u) {
            const int i = tid + (bt * 6 + u) * 256;
            if (i < RTOT * 32) {
                const int idx = i >> 5, q = (i & 31) + 1;
                U2H u0, u1;
                u0.p = __builtin_amdgcn_cvt_pkrtz(tmp[u].x, tmp[u].y);
                u1.p = __builtin_amdgcn_cvt_pkrtz(tmp[u].z, tmp[u].w);
                xs[idx * RST + q] = make_uint2(u0.u, u1.u);
            }
        }
    }
    // boundary zeros: q=0 (left pad) and q=33 (right pad) of every row
    for (int i = tid; i < 2 * RTOT; i += 256)
        xs[(i >> 1) * RST + (i & 1) * 33] = make_uint2(0u, 0u);

    // ---- weight chunk loader: coalesced uint4 from wgpT (or dense fallback) ----
    auto load_w = [&](int c, uint4* w, float& bv) {
        const int pr = c * 128 + pairbase;
        if (pr >= NK) return;
        if constexpr (USE_WG) {
            const uint4* wt4 = reinterpret_cast<const uint4*>(wgpT);
#pragma unroll
            for (int j = 0; j < 10; ++j) w[j] = wt4[(size_t)(half * 10 + j) * NK + pr];
        } else {
            const int ki = pr / 25, kj = pr - ki * 25;
            const int o = (5 * kj + 2) & 3;
#pragma unroll
            for (int j = 0; j < 10; ++j) {
                const int di = di0 + (j >> 1), pb = (j & 1) * 8;
                unsigned int uu[4];
#pragma unroll
                for (int m = 0; m < 4; ++m) {
                    float f0 = 0.f, f1 = 0.f;
                    const int j0 = pb + 2 * m - o, j1 = pb + 2 * m + 1 - o;
                    const size_t rowb = (size_t)((ki * 5 + di) * WPADR + kj * 5);
                    if (j0 >= 0 && j0 < 10) f0 = Wfull[(rowb + j0) * NK + pr];
                    if (j1 >= 0 && j1 < 10) f1 = Wfull[(rowb + j1) * NK + pr];
                    U2H u; u.p = __builtin_amdgcn_cvt_pkrtz(f0, f1);
                    uu[m] = u.u;
                }
                w[j] = make_uint4(uu[0], uu[1], uu[2], uu[3]);
            }
        }
        if (half == 0) bv = bias[pr];
    };

    auto compute_chunk = [&](int c, const uint4* w, float bv) {
        const int pr = c * 128 + pairbase;
        float acc0 = 0.f, acc1 = 0.f;
        if (pr < NK) {
            const int ki = pr / 25, kj = pr - ki * 25;
            // staged row index of tap (d) for this half: 5*ki + di0 + d
            const uint2* base = xs + (5 * ki + di0) * RST + ((5 * kj + 2) >> 2);
#pragma unroll
            for (int d = 0; d < 5; ++d) {
                const uint2* rowp = base + d * RST;
                const uint2 a0 = rowp[0], a1 = rowp[1], a2 = rowp[2], a3 = rowp[3];
                const uint4 wA = w[2 * d], wB = w[2 * d + 1];
                acc0 = dot2acc(a0.x, wA.x, acc0);
                acc1 = dot2acc(a0.y, wA.y, acc1);
                acc0 = dot2acc(a1.x, wA.z, acc0);
                acc1 = dot2acc(a1.y, wA.w, acc1);
                acc0 = dot2acc(a2.x, wB.x, acc0);
                acc1 = dot2acc(a2.y, wB.y, acc1);
                acc0 = dot2acc(a3.x, wB.z, acc0);
                acc1 = dot2acc(a3.y, wB.w, acc1);
            }
        }
        // combine lane pair (l, l^32) within the wave; half 0 stores
        float acc = acc0 + acc1;
        float other = __shfl_xor(acc, 32, 64);
        if (pr < NK && half == 0)
            out[(size_t)b * NK + pr] = acc + other + bv;
    };

    // ---- 5 chunks, double-buffered weights (all indices compile-time) ----
    uint4 wA[10], wB[10];
    float bA = 0.f, bB = 0.f;
    load_w(0, wA, bA);                      // issued before barrier: global-only
    load_w(1, wB, bB);
    __syncthreads();
    compute_chunk(0, wA, bA); load_w(2, wA, bA);
    compute_chunk(1, wB, bB); load_w(3, wB, bB);
    compute_chunk(2, wA, bA); load_w(4, wA, bA);
    compute_chunk(3, wB, bB);
    compute_chunk(4, wA, bA);
}

extern "C" void kernel_launch(void* const* d_in, const int* in_sizes, int n_in,
                              void* d_out, int out_size, void* d_ws, size_t ws_size,
                              hipStream_t stream) {
    const float* x    = (const float*)d_in[0];
    const float* W    = (const float*)d_in[1];
    const float* bias = (const float*)d_in[2];
    float* out = (float*)d_out;

    const dim3 grid(1024);                  // one block per image, whole grid resident
    if (ws_size >= (size_t)NK * WPT * sizeof(_Float16)) {
        _Float16* wgpT = (_Float16*)d_ws;
        gather_wp<<<(NK * WPT + 255) / 256, 256, 0, stream>>>(W, wgpT);
        lc2d_img<true><<<grid, 256, 0, stream>>>(x, wgpT, W, bias, out);
    } else {
        lc2d_img<false><<<grid, 256, 0, stream>>>(x, nullptr, W, bias, out);
    }
}

// Round 3
// 126.607 us; speedup vs baseline: 1.1884x; 1.0007x over previous
//
#include <hip/hip_runtime.h>

typedef _Float16 f16x2 __attribute__((ext_vector_type(2)));
typedef __fp16  fp16x2 __attribute__((ext_vector_type(2)));

// Problem constants
constexpr int NKW  = 25, NK = 625;
constexpr int WPADR = 132;                  // reference padded width
constexpr int WPT   = 160;                  // padded halves per (ki,kj) weight row
constexpr int RST   = 35;                   // LDS row stride in uint2 (+1 anti-conflict)
constexpr int RTOT  = 132;                  // staged rows: 2 pad + 128 + 2 pad
constexpr int NITEM = RTOT * 32;            // 4224 staged float4 items

union U2H { unsigned int u; f16x2 h; fp16x2 p; };

// ---- gather: dense W -> f16 weights, zero-padded 16-slot rows, TRANSPOSED ----
// wgpT as uint4[20][625]; slot j of output k holds padded halves 8j..8j+7.
// Real data at in-row slot o..o+9, o = (5*kj+2) & 3, matching aligned LDS
// window h0 = (5*kj+2) & ~3.  (unchanged, verified in earlier rounds)
__global__ void gather_wp(const float* __restrict__ W, _Float16* __restrict__ wgpT) {
    int t = blockIdx.x * 256 + threadIdx.x;
    if (t >= NK * WPT) return;
    int k = t / WPT, p = t % WPT;
    int di = p >> 4, s = p & 15;
    int ki = k / NKW, kj = k % NKW;
    int o = (5 * kj + 2) & 3;
    int j = s - o;
    float val = 0.f;
    if (j >= 0 && j < 10)
        val = W[(size_t)((ki * 5 + di) * WPADR + kj * 5 + j) * NK + k];
    wgpT[((size_t)(p >> 3) * NK + k) * 8 + (p & 7)] = (_Float16)val;
}

__device__ __forceinline__ float dot2acc(unsigned int a, unsigned int b, float c) {
    U2H ua, ub; ua.u = a; ub.u = b;
#if __has_builtin(__builtin_amdgcn_fdot2)
    return __builtin_amdgcn_fdot2(ua.h, ub.h, c, false);
#else
    return c + (float)ua.h.x * (float)ub.h.x + (float)ua.h.y * (float)ub.h.y;
#endif
}

// R16: one-image-per-block, de-spilled + split-barrier overlap.
// R15 post-mortem: lc2d_img was ~40us (vs 18-20 predicted). Suspects:
// (1) wA+wB double-buffer = 80 VGPR under launch_bounds(256,4)'s 128-cap ->
//     scratch spills; (2) fully serial stage(10.6us HBM)->barrier->compute.
// Fix: single wq[10] buffer (TLP hides L2 weight latency between chunks;
// 16 waves/CU), and progressive staging: rows 0..63 -> barrier -> chunks 0-1
// (need rows<=59) overlapped with staging rows 64..131 (disjoint LDS, race-
// free without barrier) -> barrier -> chunks 2-4.
template <bool USE_WG>
__global__ __launch_bounds__(256, 4)
void lc2d_img(const float* __restrict__ x, const _Float16* __restrict__ wgpT,
              const float* __restrict__ Wfull,
              const float* __restrict__ bias, float* __restrict__ out) {
    __shared__ uint2 xs[RTOT * RST];        // 36960 B -> 4 blocks/CU (LDS-capped)

    const int b    = blockIdx.x;            // one image per block
    const int tid  = threadIdx.x;
    const int lane = tid & 63;
    const int pairbase = (tid >> 6) * 32 + (lane & 31);  // 0..127
    const int half = lane >> 5;             // lane pair (l, l^32) shares pairbase
    const int di0  = half * 5;              // this thread's 5 di rows
    const float* xb = x + ((size_t)b << 14);

    // ---- staging helpers: 4 items/thread per batch (16 VGPR of tmp) ----
    auto stage_load4 = [&](int u0, float4* tmp) {
#pragma unroll
        for (int u = 0; u < 4; ++u) {
            const int i = tid + (u0 + u) * 256;
            tmp[u] = make_float4(0.f, 0.f, 0.f, 0.f);
            if (i < NITEM) {
                const int idx = i >> 5, q = i & 31, r = idx - 2;
                if (r >= 0 && r < 128)
                    tmp[u] = *reinterpret_cast<const float4*>(xb + (r << 7) + (q << 2));
            }
        }
    };
    auto stage_write4 = [&](int u0, const float4* tmp) {
#pragma unroll
        for (int u = 0; u < 4; ++u) {
            const int i = tid + (u0 + u) * 256;
            if (i < NITEM) {
                const int idx = i >> 5, q = (i & 31) + 1;
                U2H u0h, u1h;
                u0h.p = __builtin_amdgcn_cvt_pkrtz(tmp[u].x, tmp[u].y);
                u1h.p = __builtin_amdgcn_cvt_pkrtz(tmp[u].z, tmp[u].w);
                xs[idx * RST + q] = make_uint2(u0h.u, u1h.u);
            }
        }
    };

    // ---- weight chunk loader: coalesced uint4 from wgpT (or dense fallback) ----
    uint4 wq[10];
    float bv = 0.f;
    auto load_w = [&](int c) {
        const int pr = c * 128 + pairbase;
        if (pr >= NK) return;
        if constexpr (USE_WG) {
            const uint4* wt4 = reinterpret_cast<const uint4*>(wgpT);
#pragma unroll
            for (int j = 0; j < 10; ++j) wq[j] = wt4[(size_t)(half * 10 + j) * NK + pr];
        } else {
            const int ki = pr / 25, kj = pr - ki * 25;
            const int o = (5 * kj + 2) & 3;
#pragma unroll
            for (int j = 0; j < 10; ++j) {
                const int di = di0 + (j >> 1), pb = (j & 1) * 8;
                unsigned int uu[4];
#pragma unroll
                for (int m = 0; m < 4; ++m) {
                    float f0 = 0.f, f1 = 0.f;
                    const int j0 = pb + 2 * m - o, j1 = pb + 2 * m + 1 - o;
                    const size_t rowb = (size_t)((ki * 5 + di) * WPADR + kj * 5);
                    if (j0 >= 0 && j0 < 10) f0 = Wfull[(rowb + j0) * NK + pr];
                    if (j1 >= 0 && j1 < 10) f1 = Wfull[(rowb + j1) * NK + pr];
                    U2H u; u.p = __builtin_amdgcn_cvt_pkrtz(f0, f1);
                    uu[m] = u.u;
                }
                wq[j] = make_uint4(uu[0], uu[1], uu[2], uu[3]);
            }
        }
        if (half == 0) bv = bias[pr];
    };

    auto compute_chunk = [&](int c) {
        const int pr = c * 128 + pairbase;
        float acc0 = 0.f, acc1 = 0.f;
        if (pr < NK) {
            const int ki = pr / 25, kj = pr - ki * 25;
            const uint2* base = xs + (5 * ki + di0) * RST + ((5 * kj + 2) >> 2);
#pragma unroll
            for (int d = 0; d < 5; ++d) {
                const uint2* rowp = base + d * RST;
                const uint2 a0 = rowp[0], a1 = rowp[1], a2 = rowp[2], a3 = rowp[3];
                const uint4 wA = wq[2 * d], wB = wq[2 * d + 1];
                acc0 = dot2acc(a0.x, wA.x, acc0);
                acc1 = dot2acc(a0.y, wA.y, acc1);
                acc0 = dot2acc(a1.x, wA.z, acc0);
                acc1 = dot2acc(a1.y, wA.w, acc1);
                acc0 = dot2acc(a2.x, wB.x, acc0);
                acc1 = dot2acc(a2.y, wB.y, acc1);
                acc0 = dot2acc(a3.x, wB.z, acc0);
                acc1 = dot2acc(a3.y, wB.w, acc1);
            }
        }
        float acc = acc0 + acc1;
        float other = __shfl_xor(acc, 32, 64);
        if (pr < NK && half == 0)
            out[(size_t)b * NK + pr] = acc + other + bv;
    };

    // ---- boundary zeros: q=0 (left) and q=33 (right) of every row ----
    for (int i = tid; i < 2 * RTOT; i += 256)
        xs[(i >> 1) * RST + (i & 1) * 33] = make_uint2(0u, 0u);

    // ---- phase A: stage rows 0..63 (items 0..2047), weights chunk 0 ----
    {
        float4 t[4];
        stage_load4(0, t);  stage_write4(0, t);
        stage_load4(4, t);  stage_write4(4, t);
    }
    load_w(0);                              // in flight across the barrier
    __syncthreads();                        // rows 0..63 + zeros visible

    // ---- phase B: chunks 0-1 (rows <=59) overlapped with staging 64..131 ----
    {
        float4 t[4];
        stage_load4(8, t);                  // rows 64..95 in flight
        compute_chunk(0);
        load_w(1);
        stage_write4(8, t);                 // disjoint rows: no barrier needed
        stage_load4(12, t);                 // rows 96..127
        compute_chunk(1);
        load_w(2);
        stage_write4(12, t);
        // tail: items 4096..4223 (rows 128..131), tid<128 active
        float4 t1 = make_float4(0.f, 0.f, 0.f, 0.f);
        const int i16 = tid + 4096;
        if (i16 < NITEM) {
            const int idx = i16 >> 5, q = i16 & 31, r = idx - 2;
            if (r >= 0 && r < 128)
                t1 = *reinterpret_cast<const float4*>(xb + (r << 7) + (q << 2));
        }
        if (i16 < NITEM) {
            const int idx = i16 >> 5, q = (i16 & 31) + 1;
            U2H u0h, u1h;
            u0h.p = __builtin_amdgcn_cvt_pkrtz(t1.x, t1.y);
            u1h.p = __builtin_amdgcn_cvt_pkrtz(t1.z, t1.w);
            xs[idx * RST + q] = make_uint2(u0h.u, u1h.u);
        }
    }
    __syncthreads();                        // rows 64..131 visible

    // ---- phase C: chunks 2-4 (rows 50..131) ----
    compute_chunk(2);
    load_w(3);
    compute_chunk(3);
    load_w(4);
    compute_chunk(4);
}

extern "C" void kernel_launch(void* const* d_in, const int* in_sizes, int n_in,
                              void* d_out, int out_size, void* d_ws, size_t ws_size,
                              hipStream_t stream) {
    const float* x    = (const float*)d_in[0];
    const float* W    = (const float*)d_in[1];
    const float* bias = (const float*)d_in[2];
    float* out = (float*)d_out;

    const dim3 grid(1024);                  // one block per image, whole grid resident
    if (ws_size >= (size_t)NK * WPT * sizeof(_Float16)) {
        _Float16* wgpT = (_Float16*)d_ws;
        gather_wp<<<(NK * WPT + 255) / 256, 256, 0, stream>>>(W, wgpT);
        lc2d_img<true><<<grid, 256, 0, stream>>>(x, wgpT, W, bias, out);
    } else {
        lc2d_img<false><<<grid, 256, 0, stream>>>(x, nullptr, W, bias, out);
    }
}